// Round 19
// baseline (532.835 us; speedup 1.0000x reference)
//
#include <hip/hip_runtime.h>

// CorrelationCost (tfa): out[b, dy*9+dx, y, x] =
//   (1/128) * sum_c prv[b,c,y,x] * nxt[b,c,y+dy-4,x+dx-4], zero-padded.
// B=4, C=128, H=128, W=256 -> out [4, 81, 128, 256] fp32.
//
// R18 -> R19: R14 structure + 2-deep N prefetch. In R14 the N loads for
// pair k+1 are issued at iter-k top and waited at iter-k end (~190 cy
// window) vs ~200-500 cy L2/L3 latency -- the exposed stall. Now N(k+2)
// is issued at iter-k top and PKN(k+1) waits on loads a full iteration
// old. P path keeps its (already full-iteration) 1-deep window. Rolled
// loop pinned (unroll 1): R15/R16 proved unrolling this body spills.

#define SR 4
#define ND 9
#define BB 4
#define CC 128
#define HH 128
#define WW 256
#define HW (HH * WW)
#define PADW 264      // 4 left pad + 256 px + 4 right pad (u32 = h2 pair)
#define RSTR 40       // reduction lane stride (u32)

typedef __fp16 h2 __attribute__((ext_vector_type(2)));

static __device__ __forceinline__ h2 pk(float lo, float hi) {
    return __builtin_amdgcn_cvt_pkrtz(lo, hi);   // v_cvt_pkrtz_f16_f32
}
static __device__ __forceinline__ h2 as_h2(unsigned u) {
    union { unsigned u; h2 h; } v; v.u = u; return v.h;
}
static __device__ __forceinline__ unsigned as_u32(h2 h) {
    union { unsigned u; h2 h; } v; v.h = h; return v.u;
}

#define CFENCE asm volatile("" ::: "memory")

__global__ __launch_bounds__(256, 3) void costvol_kernel(
    const float* __restrict__ prv,
    const float* __restrict__ nxt,
    float* __restrict__ out)
{
    // staging: [4 waves][2 bufs][3 rows][PADW] = 6336 u32 = 25344 B
    // reduction union: 2 regions x 64 lanes x RSTR = 5120 u32 (staging dead)
    __shared__ unsigned shraw[4 * 2 * 3 * PADW];

    // XCD-chunked bijective swizzle (768 % 8 == 0).
    const int nwg  = gridDim.x;
    const int cpx  = nwg >> 3;                 // 96
    const int orig = blockIdx.x;
    const int wid  = (orig & 7) * cpx + (orig >> 3);

    // g fastest: the 3 dy-groups sharing (b, y-pair) are L2-local.
    const int g  = wid % 3;
    const int r_ = wid / 3;
    const int yp = r_ & 63;
    const int b  = r_ >> 6;

    const int tid  = threadIdx.x;
    const int w    = tid >> 6;                 // wave 0..3
    const int lane = tid & 63;
    const int ry   = w & 1;                    // y row in pair
    const int ch   = w >> 1;                   // channel half
    const int x0   = lane << 2;                // 4 px per lane
    const int y    = (yp << 1) + ry;
    const int r0   = y + 3 * g - SR;           // first of 3 nxt rows

    bool vok[3];
    #pragma unroll
    for (int j = 0; j < 3; ++j)
        vok[j] = ((unsigned)(r0 + j) < (unsigned)HH);

    unsigned* stg = shraw + w * (2 * 3 * PADW);   // wave-private staging

    // Zero the 4-u32 pads: 2 buf x 3 rows x 2 ends = 12 per wave, once.
    if (lane < 12) {
        const int e  = lane >= 6 ? 1 : 0;
        const int q  = lane - 6 * e;
        const int bf = q & 1;
        const int j  = q >> 1;
        *reinterpret_cast<uint4*>(stg + (bf * 3 + j) * PADW + (e ? 260 : 0)) =
            make_uint4(0u, 0u, 0u, 0u);
    }

    const size_t cbase = (size_t)(b * CC + (ch << 6)) * HW;
    const float* pg = prv + cbase + (size_t)y * WW + x0;
    const float* ng = nxt + cbase + (ptrdiff_t)r0 * WW + x0;

    float acc[3][ND][4];
    #pragma unroll
    for (int j = 0; j < 3; ++j)
        #pragma unroll
        for (int dx = 0; dx < ND; ++dx)
            #pragma unroll
            for (int px = 0; px < 4; ++px)
                acc[j][dx][px] = 0.f;

    #define LOADN(k, N) do { \
        const float* nn_ = ng + (size_t)(2 * (k)) * HW; \
        _Pragma("unroll") \
        for (int j_ = 0; j_ < 3; ++j_) { \
            if (vok[j_]) { \
                N[j_][0] = *reinterpret_cast<const float4*>(nn_ + j_ * WW); \
                N[j_][1] = *reinterpret_cast<const float4*>(nn_ + j_ * WW + HW); \
            } else { \
                N[j_][0] = make_float4(0.f, 0.f, 0.f, 0.f); \
                N[j_][1] = make_float4(0.f, 0.f, 0.f, 0.f); \
            } \
        } } while (0)

    #define LOADPP(k, P0, P1) do { \
        const float* pp_ = pg + (size_t)(2 * (k)) * HW; \
        P0 = *reinterpret_cast<const float4*>(pp_); \
        P1 = *reinterpret_cast<const float4*>(pp_ + HW); } while (0)

    #define PKN(NH, N) do { \
        _Pragma("unroll") \
        for (int j_ = 0; j_ < 3; ++j_) { \
            NH[j_][0] = as_u32(pk(N[j_][0].x, N[j_][1].x)); \
            NH[j_][1] = as_u32(pk(N[j_][0].y, N[j_][1].y)); \
            NH[j_][2] = as_u32(pk(N[j_][0].z, N[j_][1].z)); \
            NH[j_][3] = as_u32(pk(N[j_][0].w, N[j_][1].w)); \
        } } while (0)

    #define STAGE(bf, NH) do { \
        _Pragma("unroll") \
        for (int j_ = 0; j_ < 3; ++j_) \
            *reinterpret_cast<uint4*>(stg + ((bf) * 3 + j_) * PADW + 4 + x0) = \
                make_uint4(NH[j_][0], NH[j_][1], NH[j_][2], NH[j_][3]); \
        } while (0)

    float4 P0c, P1c, P0n, P1n, Nn1[3][2], Nn2[3][2];
    unsigned nhc[3][4], nhn[3][4];

    // Prologue: N(0)+P(0) issued; pair 0 packed+staged; N(1) issued.
    LOADN(0, Nn1);
    LOADPP(0, P0c, P1c);
    PKN(nhc, Nn1);                      // waits N(0)
    STAGE(0, nhc);
    LOADN(1, Nn1);                      // in flight across iter 0's dots
    CFENCE;

    // Invariant at iter k: nhc = packed N(k); buf[k&1] = N(k) staged;
    // P0c/P1c = P(k) (arrived); Nn1 = N(k+1) in flight (issued >= 1 full
    // iteration before its PKN wait).
    #pragma unroll 1
    for (int k = 0; k < 32; ++k) {
        const int bf = k & 1;
        if (k < 31) LOADPP(k + 1, P0n, P1n);    // used next iter top
        if (k < 30) LOADN(k + 2, Nn2);          // consumed end of next iter

        h2 ph[4];
        ph[0] = pk(P0c.x, P1c.x); ph[1] = pk(P0c.y, P1c.y);
        ph[2] = pk(P0c.z, P1c.z); ph[3] = pk(P0c.w, P1c.w);

        #pragma unroll
        for (int j = 0; j < 3; ++j) {
            const unsigned* row = stg + (bf * 3 + j) * PADW;
            const uint4 wl = *reinterpret_cast<const uint4*>(row + x0);
            const uint4 wr = *reinterpret_cast<const uint4*>(row + x0 + 8);
            h2 n12[12];
            n12[0] = as_h2(wl.x); n12[1] = as_h2(wl.y);
            n12[2] = as_h2(wl.z); n12[3] = as_h2(wl.w);
            n12[4] = as_h2(nhc[j][0]); n12[5] = as_h2(nhc[j][1]);
            n12[6] = as_h2(nhc[j][2]); n12[7] = as_h2(nhc[j][3]);
            n12[8] = as_h2(wr.x); n12[9] = as_h2(wr.y);
            n12[10] = as_h2(wr.z); n12[11] = as_h2(wr.w);
            #pragma unroll
            for (int dx = 0; dx < ND; ++dx)
                #pragma unroll
                for (int px = 0; px < 4; ++px)
                    acc[j][dx][px] =
                        __builtin_amdgcn_fdot2(ph[px], n12[dx + px], acc[j][dx][px], false);
        }

        if (k < 31) {
            PKN(nhn, Nn1);                   // waits N(k+1), issued >=1 iter ago
            STAGE(bf ^ 1, nhn);
            CFENCE;                          // next iter's reads stay below
            P0c = P0n; P1c = P1n;
            #pragma unroll
            for (int j = 0; j < 3; ++j)
                #pragma unroll
                for (int i = 0; i < 4; ++i)
                    nhc[j][i] = nhn[j][i];
            if (k < 30) {
                #pragma unroll
                for (int j = 0; j < 3; ++j) {
                    Nn1[j][0] = Nn2[j][0];
                    Nn1[j][1] = Nn2[j][1];
                }
            }
        }
    }
    #undef STAGE
    #undef PKN
    #undef LOADPP
    #undef LOADN

    // ---- c-half reduction + output, 3 dy-chunks (staging area reused) ----
    const float invc = 1.0f / (float)CC;
    #pragma unroll
    for (int j = 0; j < 3; ++j) {
        __syncthreads();                    // prior chunk reads / loop LDS done
        if (ch == 1) {
            float* red = reinterpret_cast<float*>(shraw) + ((ry << 6) + lane) * RSTR;
            #pragma unroll
            for (int dx = 0; dx < ND; ++dx)
                *reinterpret_cast<float4*>(red + (dx << 2)) =
                    make_float4(acc[j][dx][0], acc[j][dx][1],
                                acc[j][dx][2], acc[j][dx][3]);
        }
        __syncthreads();
        if (ch == 0) {
            const float* red = reinterpret_cast<const float*>(shraw) + ((ry << 6) + lane) * RSTR;
            const int dy = 3 * g + j;
            #pragma unroll
            for (int dx = 0; dx < ND; ++dx) {
                const float4 t = *reinterpret_cast<const float4*>(red + (dx << 2));
                float* op = out + ((size_t)(b * 81 + dy * ND + dx) * HH + y) * WW + x0;
                *reinterpret_cast<float4*>(op) = make_float4(
                    (acc[j][dx][0] + t.x) * invc, (acc[j][dx][1] + t.y) * invc,
                    (acc[j][dx][2] + t.z) * invc, (acc[j][dx][3] + t.w) * invc);
            }
        }
    }
}

extern "C" void kernel_launch(void* const* d_in, const int* in_sizes, int n_in,
                              void* d_out, int out_size, void* d_ws, size_t ws_size,
                              hipStream_t stream) {
    const float* prv = (const float*)d_in[0];
    const float* nxt = (const float*)d_in[1];
    float* out = (float*)d_out;

    const int nblocks = BB * (HH / 2) * 3;   // 4 * 64 * 3 = 768
    costvol_kernel<<<nblocks, 256, 0, stream>>>(prv, nxt, out);
}

// Round 20
// 398.629 us; speedup vs baseline: 1.3367x; 1.3367x over previous
//
#include <hip/hip_runtime.h>

// CorrelationCost (tfa): out[b, dy*9+dx, y, x] =
//   (1/128) * sum_c prv[b,c,y,x] * nxt[b,c,y+dy-4,x+dx-4], zero-padded.
// B=4, C=128, H=128, W=256 -> out [4, 81, 128, 256] fp32.
//
// FINAL (= R14/R18, verified 50.6 us, absmax 2e-3): dy-triplet + c-half.
// Block = (b, y-pair, dy-triplet g); 4 waves = 2 rows x 2 channel-halves
// (32 ch-pairs each); 768 blocks = 12 waves/CU co-resident. f16 dot2
// (v_dot2_f32_f16, fp32 accum) with on-the-fly cvt_pkrtz. nxt rows staged
// in wave-private padded LDS rows (double-buffered, compiler-fence only,
// no barriers in main loop). Epilogue: c-half LDS reduction, 3 dy-chunks.
//
// Closed explorations: 1-deep prefetch is the register-budget maximum
// (2-deep: +48 live regs -> spill, 533 us R19; manual unroll -> spill,
// R15/R16); MFMA Gram-band structurally worse (66-115 us, R9-R12);
// occupancy x2/x4 splits neutral (R8/R17). Plateau is multi-pipe
// latency-bound: VALU 36%, L1/L2 ~55% of floor, HBM 18%, conflicts ~0.

#define SR 4
#define ND 9
#define BB 4
#define CC 128
#define HH 128
#define WW 256
#define HW (HH * WW)
#define PADW 264      // 4 left pad + 256 px + 4 right pad (u32 = h2 pair)
#define RSTR 40       // reduction lane stride (u32)

typedef __fp16 h2 __attribute__((ext_vector_type(2)));

static __device__ __forceinline__ h2 pk(float lo, float hi) {
    return __builtin_amdgcn_cvt_pkrtz(lo, hi);   // v_cvt_pkrtz_f16_f32
}
static __device__ __forceinline__ h2 as_h2(unsigned u) {
    union { unsigned u; h2 h; } v; v.u = u; return v.h;
}
static __device__ __forceinline__ unsigned as_u32(h2 h) {
    union { unsigned u; h2 h; } v; v.h = h; return v.u;
}

#define CFENCE asm volatile("" ::: "memory")

__global__ __launch_bounds__(256, 3) void costvol_kernel(
    const float* __restrict__ prv,
    const float* __restrict__ nxt,
    float* __restrict__ out)
{
    // staging: [4 waves][2 bufs][3 rows][PADW] = 6336 u32 = 25344 B
    // reduction union: 2 regions x 64 lanes x RSTR = 5120 u32 (staging dead)
    __shared__ unsigned shraw[4 * 2 * 3 * PADW];

    // XCD-chunked bijective swizzle (768 % 8 == 0).
    const int nwg  = gridDim.x;
    const int cpx  = nwg >> 3;                 // 96
    const int orig = blockIdx.x;
    const int wid  = (orig & 7) * cpx + (orig >> 3);

    // g fastest: the 3 dy-groups sharing (b, y-pair) are L2-local.
    const int g  = wid % 3;
    const int r_ = wid / 3;
    const int yp = r_ & 63;
    const int b  = r_ >> 6;

    const int tid  = threadIdx.x;
    const int w    = tid >> 6;                 // wave 0..3
    const int lane = tid & 63;
    const int ry   = w & 1;                    // y row in pair
    const int ch   = w >> 1;                   // channel half
    const int x0   = lane << 2;                // 4 px per lane
    const int y    = (yp << 1) + ry;
    const int r0   = y + 3 * g - SR;           // first of 3 nxt rows

    bool vok[3];
    #pragma unroll
    for (int j = 0; j < 3; ++j)
        vok[j] = ((unsigned)(r0 + j) < (unsigned)HH);

    unsigned* stg = shraw + w * (2 * 3 * PADW);   // wave-private staging

    // Zero the 4-u32 pads: 2 buf x 3 rows x 2 ends = 12 per wave, once.
    if (lane < 12) {
        const int e  = lane >= 6 ? 1 : 0;
        const int q  = lane - 6 * e;
        const int bf = q & 1;
        const int j  = q >> 1;
        *reinterpret_cast<uint4*>(stg + (bf * 3 + j) * PADW + (e ? 260 : 0)) =
            make_uint4(0u, 0u, 0u, 0u);
    }

    const size_t cbase = (size_t)(b * CC + (ch << 6)) * HW;
    const float* pg = prv + cbase + (size_t)y * WW + x0;
    const float* ng = nxt + cbase + (ptrdiff_t)r0 * WW + x0;

    float acc[3][ND][4];
    #pragma unroll
    for (int j = 0; j < 3; ++j)
        #pragma unroll
        for (int dx = 0; dx < ND; ++dx)
            #pragma unroll
            for (int px = 0; px < 4; ++px)
                acc[j][dx][px] = 0.f;

    #define LOADP(k, P0, P1, N) do { \
        const float* pp_ = pg + (size_t)(2 * (k)) * HW; \
        P0 = *reinterpret_cast<const float4*>(pp_); \
        P1 = *reinterpret_cast<const float4*>(pp_ + HW); \
        const float* nn_ = ng + (size_t)(2 * (k)) * HW; \
        _Pragma("unroll") \
        for (int j_ = 0; j_ < 3; ++j_) { \
            if (vok[j_]) { \
                N[j_][0] = *reinterpret_cast<const float4*>(nn_ + j_ * WW); \
                N[j_][1] = *reinterpret_cast<const float4*>(nn_ + j_ * WW + HW); \
            } else { \
                N[j_][0] = make_float4(0.f, 0.f, 0.f, 0.f); \
                N[j_][1] = make_float4(0.f, 0.f, 0.f, 0.f); \
            } \
        } } while (0)

    #define PKN(NH, N) do { \
        _Pragma("unroll") \
        for (int j_ = 0; j_ < 3; ++j_) { \
            NH[j_][0] = as_u32(pk(N[j_][0].x, N[j_][1].x)); \
            NH[j_][1] = as_u32(pk(N[j_][0].y, N[j_][1].y)); \
            NH[j_][2] = as_u32(pk(N[j_][0].z, N[j_][1].z)); \
            NH[j_][3] = as_u32(pk(N[j_][0].w, N[j_][1].w)); \
        } } while (0)

    #define STAGE(bf, NH) do { \
        _Pragma("unroll") \
        for (int j_ = 0; j_ < 3; ++j_) \
            *reinterpret_cast<uint4*>(stg + ((bf) * 3 + j_) * PADW + 4 + x0) = \
                make_uint4(NH[j_][0], NH[j_][1], NH[j_][2], NH[j_][3]); \
        } while (0)

    float4 P0c, P1c, P0n, P1n, Nc[3][2], Nn[3][2];
    unsigned nhc[3][4], nhn[3][4];

    // Prologue: pair 0 loaded, packed, staged to buf0.
    LOADP(0, P0c, P1c, Nc);
    PKN(nhc, Nc);
    STAGE(0, nhc);
    CFENCE;

    #pragma unroll 1
    for (int k = 0; k < 32; ++k) {
        const int bf = k & 1;
        if (k < 31) LOADP(k + 1, P0n, P1n, Nn);   // in flight during dots

        h2 ph[4];
        ph[0] = pk(P0c.x, P1c.x); ph[1] = pk(P0c.y, P1c.y);
        ph[2] = pk(P0c.z, P1c.z); ph[3] = pk(P0c.w, P1c.w);

        #pragma unroll
        for (int j = 0; j < 3; ++j) {
            const unsigned* row = stg + (bf * 3 + j) * PADW;
            const uint4 wl = *reinterpret_cast<const uint4*>(row + x0);
            const uint4 wr = *reinterpret_cast<const uint4*>(row + x0 + 8);
            h2 n12[12];
            n12[0] = as_h2(wl.x); n12[1] = as_h2(wl.y);
            n12[2] = as_h2(wl.z); n12[3] = as_h2(wl.w);
            n12[4] = as_h2(nhc[j][0]); n12[5] = as_h2(nhc[j][1]);
            n12[6] = as_h2(nhc[j][2]); n12[7] = as_h2(nhc[j][3]);
            n12[8] = as_h2(wr.x); n12[9] = as_h2(wr.y);
            n12[10] = as_h2(wr.z); n12[11] = as_h2(wr.w);
            #pragma unroll
            for (int dx = 0; dx < ND; ++dx)
                #pragma unroll
                for (int px = 0; px < 4; ++px)
                    acc[j][dx][px] =
                        __builtin_amdgcn_fdot2(ph[px], n12[dx + px], acc[j][dx][px], false);
        }

        if (k < 31) {
            PKN(nhn, Nn);                    // vmcnt wait lands here, post-dots
            STAGE(bf ^ 1, nhn);
            CFENCE;                          // next iter's reads stay below
            P0c = P0n; P1c = P1n;
            #pragma unroll
            for (int j = 0; j < 3; ++j)
                #pragma unroll
                for (int i = 0; i < 4; ++i)
                    nhc[j][i] = nhn[j][i];
        }
    }
    #undef STAGE
    #undef PKN
    #undef LOADP

    // ---- c-half reduction + output, 3 dy-chunks (staging area reused) ----
    const float invc = 1.0f / (float)CC;
    #pragma unroll
    for (int j = 0; j < 3; ++j) {
        __syncthreads();                    // prior chunk reads / loop LDS done
        if (ch == 1) {
            float* red = reinterpret_cast<float*>(shraw) + ((ry << 6) + lane) * RSTR;
            #pragma unroll
            for (int dx = 0; dx < ND; ++dx)
                *reinterpret_cast<float4*>(red + (dx << 2)) =
                    make_float4(acc[j][dx][0], acc[j][dx][1],
                                acc[j][dx][2], acc[j][dx][3]);
        }
        __syncthreads();
        if (ch == 0) {
            const float* red = reinterpret_cast<const float*>(shraw) + ((ry << 6) + lane) * RSTR;
            const int dy = 3 * g + j;
            #pragma unroll
            for (int dx = 0; dx < ND; ++dx) {
                const float4 t = *reinterpret_cast<const float4*>(red + (dx << 2));
                float* op = out + ((size_t)(b * 81 + dy * ND + dx) * HH + y) * WW + x0;
                *reinterpret_cast<float4*>(op) = make_float4(
                    (acc[j][dx][0] + t.x) * invc, (acc[j][dx][1] + t.y) * invc,
                    (acc[j][dx][2] + t.z) * invc, (acc[j][dx][3] + t.w) * invc);
            }
        }
    }
}

extern "C" void kernel_launch(void* const* d_in, const int* in_sizes, int n_in,
                              void* d_out, int out_size, void* d_ws, size_t ws_size,
                              hipStream_t stream) {
    const float* prv = (const float*)d_in[0];
    const float* nxt = (const float*)d_in[1];
    float* out = (float*)d_out;

    const int nblocks = BB * (HH / 2) * 3;   // 4 * 64 * 3 = 768
    costvol_kernel<<<nblocks, 256, 0, stream>>>(prv, nxt, out);
}

// Round 21
// 50.750 us; speedup vs baseline: 10.4992x; 7.8548x over previous
//
#include <hip/hip_runtime.h>

// CorrelationCost (tfa): out[b, dy*9+dx, y, x] =
//   (1/128) * sum_c prv[b,c,y,x] * nxt[b,c,y+dy-4,x+dx-4], zero-padded.
// B=4, C=128, H=128, W=256 -> out [4, 81, 128, 256] fp32.
//
// FINAL (= R14/R18 byte-for-byte, verified 50.6-51.1 us, absmax 2e-3):
// dy-triplet + c-half hybrid. Block = (b, y-pair, dy-triplet g); 4 waves =
// 2 rows x 2 channel-halves (32 ch-pairs each); 768 blocks = 12 waves/CU.
// f16 dot2 (v_dot2_f32_f16, fp32 accum), cvt_pkrtz on the fly; nxt rows in
// wave-private padded LDS (double-buffered, compiler fence only). Epilogue:
// c-half LDS reduction in 3 dy-chunks.
//
// DO NOT add pragmas or restructure the main loop: this body sits on a
// regalloc knife-edge. R20 proved even `#pragma unroll 1` flips it to
// accumulator spill (399 us); manual 2x unroll (R15/R16) and 2-deep
// prefetch (R19) also spill. The compiler's own partial unroll of THIS
// exact rolled form is the only spill-free schedule found.

#define SR 4
#define ND 9
#define BB 4
#define CC 128
#define HH 128
#define WW 256
#define HW (HH * WW)
#define PADW 264      // 4 left pad + 256 px + 4 right pad (u32 = h2 pair)
#define RSTR 40       // reduction lane stride (u32)

typedef __fp16 h2 __attribute__((ext_vector_type(2)));

static __device__ __forceinline__ h2 pk(float lo, float hi) {
    return __builtin_amdgcn_cvt_pkrtz(lo, hi);   // v_cvt_pkrtz_f16_f32
}
static __device__ __forceinline__ h2 as_h2(unsigned u) {
    union { unsigned u; h2 h; } v; v.u = u; return v.h;
}
static __device__ __forceinline__ unsigned as_u32(h2 h) {
    union { unsigned u; h2 h; } v; v.h = h; return v.u;
}

#define CFENCE asm volatile("" ::: "memory")

__global__ __launch_bounds__(256, 3) void costvol_kernel(
    const float* __restrict__ prv,
    const float* __restrict__ nxt,
    float* __restrict__ out)
{
    // staging: [4 waves][2 bufs][3 rows][PADW] = 6336 u32 = 25344 B
    // reduction union: 2 regions x 64 lanes x RSTR = 5120 u32 (staging dead)
    __shared__ unsigned shraw[4 * 2 * 3 * PADW];

    // XCD-chunked bijective swizzle (768 % 8 == 0).
    const int nwg  = gridDim.x;
    const int cpx  = nwg >> 3;                 // 96
    const int orig = blockIdx.x;
    const int wid  = (orig & 7) * cpx + (orig >> 3);

    // g fastest: the 3 dy-groups sharing (b, y-pair) are L2-local.
    const int g  = wid % 3;
    const int r_ = wid / 3;
    const int yp = r_ & 63;
    const int b  = r_ >> 6;

    const int tid  = threadIdx.x;
    const int w    = tid >> 6;                 // wave 0..3
    const int lane = tid & 63;
    const int ry   = w & 1;                    // y row in pair
    const int ch   = w >> 1;                   // channel half
    const int x0   = lane << 2;                // 4 px per lane
    const int y    = (yp << 1) + ry;
    const int r0   = y + 3 * g - SR;           // first of 3 nxt rows

    bool vok[3];
    #pragma unroll
    for (int j = 0; j < 3; ++j)
        vok[j] = ((unsigned)(r0 + j) < (unsigned)HH);

    unsigned* stg = shraw + w * (2 * 3 * PADW);   // wave-private staging

    // Zero the 4-u32 pads: 2 buf x 3 rows x 2 ends = 12 per wave, once.
    if (lane < 12) {
        const int e  = lane >= 6 ? 1 : 0;
        const int q  = lane - 6 * e;
        const int bf = q & 1;
        const int j  = q >> 1;
        *reinterpret_cast<uint4*>(stg + (bf * 3 + j) * PADW + (e ? 260 : 0)) =
            make_uint4(0u, 0u, 0u, 0u);
    }

    const size_t cbase = (size_t)(b * CC + (ch << 6)) * HW;
    const float* pg = prv + cbase + (size_t)y * WW + x0;
    const float* ng = nxt + cbase + (ptrdiff_t)r0 * WW + x0;

    float acc[3][ND][4];
    #pragma unroll
    for (int j = 0; j < 3; ++j)
        #pragma unroll
        for (int dx = 0; dx < ND; ++dx)
            #pragma unroll
            for (int px = 0; px < 4; ++px)
                acc[j][dx][px] = 0.f;

    #define LOADP(k, P0, P1, N) do { \
        const float* pp_ = pg + (size_t)(2 * (k)) * HW; \
        P0 = *reinterpret_cast<const float4*>(pp_); \
        P1 = *reinterpret_cast<const float4*>(pp_ + HW); \
        const float* nn_ = ng + (size_t)(2 * (k)) * HW; \
        _Pragma("unroll") \
        for (int j_ = 0; j_ < 3; ++j_) { \
            if (vok[j_]) { \
                N[j_][0] = *reinterpret_cast<const float4*>(nn_ + j_ * WW); \
                N[j_][1] = *reinterpret_cast<const float4*>(nn_ + j_ * WW + HW); \
            } else { \
                N[j_][0] = make_float4(0.f, 0.f, 0.f, 0.f); \
                N[j_][1] = make_float4(0.f, 0.f, 0.f, 0.f); \
            } \
        } } while (0)

    #define PKN(NH, N) do { \
        _Pragma("unroll") \
        for (int j_ = 0; j_ < 3; ++j_) { \
            NH[j_][0] = as_u32(pk(N[j_][0].x, N[j_][1].x)); \
            NH[j_][1] = as_u32(pk(N[j_][0].y, N[j_][1].y)); \
            NH[j_][2] = as_u32(pk(N[j_][0].z, N[j_][1].z)); \
            NH[j_][3] = as_u32(pk(N[j_][0].w, N[j_][1].w)); \
        } } while (0)

    #define STAGE(bf, NH) do { \
        _Pragma("unroll") \
        for (int j_ = 0; j_ < 3; ++j_) \
            *reinterpret_cast<uint4*>(stg + ((bf) * 3 + j_) * PADW + 4 + x0) = \
                make_uint4(NH[j_][0], NH[j_][1], NH[j_][2], NH[j_][3]); \
        } while (0)

    float4 P0c, P1c, P0n, P1n, Nc[3][2], Nn[3][2];
    unsigned nhc[3][4], nhn[3][4];

    // Prologue: pair 0 loaded, packed, staged to buf0.
    LOADP(0, P0c, P1c, Nc);
    PKN(nhc, Nc);
    STAGE(0, nhc);
    CFENCE;

    for (int k = 0; k < 32; ++k) {
        const int bf = k & 1;
        if (k < 31) LOADP(k + 1, P0n, P1n, Nn);   // in flight during dots

        h2 ph[4];
        ph[0] = pk(P0c.x, P1c.x); ph[1] = pk(P0c.y, P1c.y);
        ph[2] = pk(P0c.z, P1c.z); ph[3] = pk(P0c.w, P1c.w);

        #pragma unroll
        for (int j = 0; j < 3; ++j) {
            const unsigned* row = stg + (bf * 3 + j) * PADW;
            const uint4 wl = *reinterpret_cast<const uint4*>(row + x0);
            const uint4 wr = *reinterpret_cast<const uint4*>(row + x0 + 8);
            h2 n12[12];
            n12[0] = as_h2(wl.x); n12[1] = as_h2(wl.y);
            n12[2] = as_h2(wl.z); n12[3] = as_h2(wl.w);
            n12[4] = as_h2(nhc[j][0]); n12[5] = as_h2(nhc[j][1]);
            n12[6] = as_h2(nhc[j][2]); n12[7] = as_h2(nhc[j][3]);
            n12[8] = as_h2(wr.x); n12[9] = as_h2(wr.y);
            n12[10] = as_h2(wr.z); n12[11] = as_h2(wr.w);
            #pragma unroll
            for (int dx = 0; dx < ND; ++dx)
                #pragma unroll
                for (int px = 0; px < 4; ++px)
                    acc[j][dx][px] =
                        __builtin_amdgcn_fdot2(ph[px], n12[dx + px], acc[j][dx][px], false);
        }

        if (k < 31) {
            PKN(nhn, Nn);                    // vmcnt wait lands here, post-dots
            STAGE(bf ^ 1, nhn);
            CFENCE;                          // next iter's reads stay below
            P0c = P0n; P1c = P1n;
            #pragma unroll
            for (int j = 0; j < 3; ++j)
                #pragma unroll
                for (int i = 0; i < 4; ++i)
                    nhc[j][i] = nhn[j][i];
        }
    }
    #undef STAGE
    #undef PKN
    #undef LOADP

    // ---- c-half reduction + output, 3 dy-chunks (staging area reused) ----
    const float invc = 1.0f / (float)CC;
    #pragma unroll
    for (int j = 0; j < 3; ++j) {
        __syncthreads();                    // prior chunk reads / loop LDS done
        if (ch == 1) {
            float* red = reinterpret_cast<float*>(shraw) + ((ry << 6) + lane) * RSTR;
            #pragma unroll
            for (int dx = 0; dx < ND; ++dx)
                *reinterpret_cast<float4*>(red + (dx << 2)) =
                    make_float4(acc[j][dx][0], acc[j][dx][1],
                                acc[j][dx][2], acc[j][dx][3]);
        }
        __syncthreads();
        if (ch == 0) {
            const float* red = reinterpret_cast<const float*>(shraw) + ((ry << 6) + lane) * RSTR;
            const int dy = 3 * g + j;
            #pragma unroll
            for (int dx = 0; dx < ND; ++dx) {
                const float4 t = *reinterpret_cast<const float4*>(red + (dx << 2));
                float* op = out + ((size_t)(b * 81 + dy * ND + dx) * HH + y) * WW + x0;
                *reinterpret_cast<float4*>(op) = make_float4(
                    (acc[j][dx][0] + t.x) * invc, (acc[j][dx][1] + t.y) * invc,
                    (acc[j][dx][2] + t.z) * invc, (acc[j][dx][3] + t.w) * invc);
            }
        }
    }
}

extern "C" void kernel_launch(void* const* d_in, const int* in_sizes, int n_in,
                              void* d_out, int out_size, void* d_ws, size_t ws_size,
                              hipStream_t stream) {
    const float* prv = (const float*)d_in[0];
    const float* nxt = (const float*)d_in[1];
    float* out = (float*)d_out;

    const int nblocks = BB * (HH / 2) * 3;   // 4 * 64 * 3 = 768
    costvol_kernel<<<nblocks, 256, 0, stream>>>(prv, nxt, out);
}